// Round 19
// baseline (499.381 us; speedup 1.0000x reference)
//
#include <hip/hip_runtime.h>
#include <hip/hip_bf16.h>

#define NN  100000
#define NE  1600000
#define NH4 400000      // N*H
#define NHC 12800000    // N*HC
#define NBLK 391        // ceil(NN/256)
#define SC_CHUNK 2048
#define SC_NCHUNK ((NE + SC_CHUNK - 1) / SC_CHUNK)  // 782 (hist)
#define SG_CHUNK 8192
#define SG_NCHUNK ((NE + SG_CHUNK - 1) / SG_CHUNK)  // 196 (fused scatter, 512 thr)
#define SCAT_BLKS (SG_NCHUNK * 8)                   // 1568 (multiple of 8)
#define NG_GEMM 782

typedef __attribute__((ext_vector_type(8))) short bf16x8;
typedef __attribute__((ext_vector_type(4))) float f32x4;

__device__ __forceinline__ ushort f2bf(float f) {  // RNE f32 -> bf16 bits
  uint u = __float_as_uint(f);
  u += 0x7fff + ((u >> 16) & 1);
  return (ushort)(u >> 16);
}
__device__ __forceinline__ uint pack2(float a, float b) {
  return (uint)f2bf(a) | ((uint)f2bf(b) << 16);
}
__device__ __forceinline__ float blo(uint u) { return __uint_as_float(u << 16); }
__device__ __forceinline__ float bhi(uint u) { return __uint_as_float(u & 0xffff0000u); }

// ================= MFMA GEMM building blocks (128 rows/block, 8 waves) ======
__device__ __forceinline__ void stage_A_bf16(const uint* __restrict__ Ab, int row0,
                                             uint* __restrict__ As, int tid) {
  const uint4* __restrict__ Ag = (const uint4*)(Ab + (size_t)row0 * 64);
#pragma unroll
  for (int i = 0; i < 4; i++) {
    const int idx = tid + 512 * i;        // uint4 idx over 128x16
    const int r = idx >> 4, c4 = idx & 15;
    uint4 v = make_uint4(0u, 0u, 0u, 0u);
    if (row0 + r < NN) v = Ag[idx];
    const uint off = (uint)(r * 64 + c4 * 4) ^ (uint)((r & 7) << 2);
    *(uint4*)&As[off] = v;
  }
}
__device__ __forceinline__ void stage_A_f32(const float* __restrict__ Af, int row0,
                                            uint* __restrict__ As, int tid) {
  const float4* __restrict__ Ag = (const float4*)(Af + (size_t)row0 * 128);
#pragma unroll
  for (int i = 0; i < 8; i++) {
    const int idx = tid + 512 * i;        // float4 idx over 128x32
    const int r = idx >> 5, k4 = idx & 31;
    float4 a = make_float4(0.f, 0.f, 0.f, 0.f);
    if (row0 + r < NN) a = Ag[idx];
    uint2 p;
    p.x = pack2(a.x, a.y);
    p.y = pack2(a.z, a.w);
    const uint off = (uint)(r * 64 + k4 * 2) ^ (uint)((r & 7) << 2);
    *(uint2*)&As[off] = p;
  }
}
// nontemporal-load variant: x is read exactly once -> evict-first.
__device__ __forceinline__ void stage_A_f32_nt(const float* __restrict__ Af, int row0,
                                               uint* __restrict__ As, int tid) {
  const f32x4* __restrict__ Ag = (const f32x4*)(Af + (size_t)row0 * 128);
#pragma unroll
  for (int i = 0; i < 8; i++) {
    const int idx = tid + 512 * i;        // float4 idx over 128x32
    const int r = idx >> 5, k4 = idx & 31;
    f32x4 a = {0.f, 0.f, 0.f, 0.f};
    if (row0 + r < NN) a = __builtin_nontemporal_load(&Ag[idx]);
    uint2 p;
    p.x = pack2(a[0], a[1]);
    p.y = pack2(a[2], a[3]);
    const uint off = (uint)(r * 64 + k4 * 2) ^ (uint)((r & 7) << 2);
    *(uint2*)&As[off] = p;
  }
}
__device__ __forceinline__ void stage_W(const float* __restrict__ W,
                                        uint* __restrict__ Wt, int tid) {
#pragma unroll
  for (int i = 0; i < 4; i++) {
    const int cid = tid + 512 * i;        // (n, k8) chunk
    const int n = cid & 127;
    const int k8 = cid >> 7;              // 0..15
    float v[8];
#pragma unroll
    for (int j = 0; j < 8; j++) v[j] = W[(size_t)(k8 * 8 + j) * 128 + n];
    uint4 p;
    p.x = pack2(v[0], v[1]);
    p.y = pack2(v[2], v[3]);
    p.z = pack2(v[4], v[5]);
    p.w = pack2(v[6], v[7]);
    const uint off = (uint)(n * 64 + k8 * 4) ^ (uint)((n & 7) << 2);
    *(uint4*)&Wt[off] = p;
  }
}
__device__ __forceinline__ void load_afrag(const uint* __restrict__ As, int w, int l,
                                           bf16x8* afrag) {
  const int lrow = l & 15, lku = (l >> 4) * 4;
#pragma unroll
  for (int kc = 0; kc < 4; kc++) {
    const int r = w * 16 + lrow;
    const uint off = (uint)(r * 64 + lku + kc * 16) ^ (uint)((r & 7) << 2);
    afrag[kc] = *(const bf16x8*)&As[off];
  }
}

// MFMA + writeback; optionally fuses the attention-coefficient epilogue.
__device__ __forceinline__ void mfma_write(const uint* __restrict__ Wt,
                                           const bf16x8* afrag, int row0, int w, int l,
                                           const float* __restrict__ bias1,
                                           const float* __restrict__ bias2,
                                           ushort* __restrict__ out,
                                           const float* __restrict__ as_,
                                           const float* __restrict__ ad_,
                                           float* __restrict__ es,
                                           float* __restrict__ ed) {
  const int lrow = l & 15, lku = (l >> 4) * 4;
  const int r0 = row0 + w * 16 + (l >> 4) * 4;
#pragma unroll
  for (int pair = 0; pair < 4; pair++) {     // head index
    float pa[4] = {0.f, 0.f, 0.f, 0.f};
    float qa[4] = {0.f, 0.f, 0.f, 0.f};
#pragma unroll
    for (int sub = 0; sub < 2; sub++) {
      const int nt = pair * 2 + sub;
      const int n = nt * 16 + lrow;
      f32x4 acc = {0.f, 0.f, 0.f, 0.f};
#pragma unroll
      for (int kc = 0; kc < 4; kc++) {
        const uint off = (uint)(n * 64 + lku + kc * 16) ^ (uint)((n & 7) << 2);
        const bf16x8 bfrag = *(const bf16x8*)&Wt[off];
        acc = __builtin_amdgcn_mfma_f32_16x16x32_bf16(afrag[kc], bfrag, acc, 0, 0, 0);
      }
      float badd = 0.f;
      if (bias1) badd += bias1[n];
      if (bias2) badd += bias2[n];
#pragma unroll
      for (int reg = 0; reg < 4; reg++) {
        const int r = r0 + reg;
        if (r < NN) out[(size_t)r * 128 + n] = f2bf(acc[reg] + badd);
      }
      if (as_) {
        const float av = as_[n], dv = ad_[n];
#pragma unroll
        for (int reg = 0; reg < 4; reg++) {
          pa[reg] = fmaf(acc[reg], av, pa[reg]);
          qa[reg] = fmaf(acc[reg], dv, qa[reg]);
        }
      }
    }
    if (as_) {
#pragma unroll
      for (int m = 1; m <= 8; m <<= 1) {
#pragma unroll
        for (int reg = 0; reg < 4; reg++) {
          pa[reg] += __shfl_xor(pa[reg], m);
          qa[reg] += __shfl_xor(qa[reg], m);
        }
      }
      if (lrow == 0) {
#pragma unroll
        for (int reg = 0; reg < 4; reg++) {
          const int r = r0 + reg;
          if (r < NN) {
            es[r * 4 + pair] = pa[reg];
            ed[r * 4 + pair] = qa[reg];
          }
        }
      }
    }
  }
}

// ---- single GEMM: out = A @ W (+biases); optional fused attn coefs ----
template <bool ABF16>
__global__ __launch_bounds__(512) void gemm128_k(const void* __restrict__ Av,
                                                 const float* __restrict__ W,
                                                 ushort* __restrict__ out,
                                                 const float* __restrict__ bias1,
                                                 const float* __restrict__ bias2,
                                                 const float* __restrict__ as_,
                                                 const float* __restrict__ ad_,
                                                 float* __restrict__ es,
                                                 float* __restrict__ ed) {
  __shared__ uint As[128 * 64];   // 32 KB
  __shared__ uint Wt[128 * 64];   // 32 KB
  const int tid = threadIdx.x;
  const int row0 = blockIdx.x * 128;
  if constexpr (ABF16) stage_A_bf16((const uint*)Av, row0, As, tid);
  else                 stage_A_f32((const float*)Av, row0, As, tid);
  stage_W(W, Wt, tid);
  __syncthreads();
  const int w = tid >> 6, l = tid & 63;
  bf16x8 afrag[4];
  load_afrag(As, w, l, afrag);
  mfma_write(Wt, afrag, row0, w, l, bias1, bias2, out, as_, ad_, es, ed);
}

// ---- dual GEMM (layer 2): A staged once; Wt restaged in place ----
__global__ __launch_bounds__(512) void gemm2_k(const uint* __restrict__ Ab,
                                               const float* __restrict__ W1,
                                               const float* __restrict__ b1a,
                                               const float* __restrict__ b1b,
                                               ushort* __restrict__ out1,
                                               const float* __restrict__ W2,
                                               ushort* __restrict__ out2,
                                               const float* __restrict__ as_,
                                               const float* __restrict__ ad_,
                                               float* __restrict__ es,
                                               float* __restrict__ ed) {
  __shared__ uint As[128 * 64];   // 32 KB
  __shared__ uint Wt[128 * 64];   // 32 KB
  const int tid = threadIdx.x;
  const int row0 = blockIdx.x * 128;
  stage_A_bf16(Ab, row0, As, tid);
  stage_W(W1, Wt, tid);
  __syncthreads();
  const int w = tid >> 6, l = tid & 63;
  bf16x8 afrag[4];
  load_afrag(As, w, l, afrag);
  mfma_write(Wt, afrag, row0, w, l, b1a, b1b, out1, nullptr, nullptr, nullptr, nullptr);
  __syncthreads();                 // all Wt reads done
  stage_W(W2, Wt, tid);
  __syncthreads();
  mfma_write(Wt, afrag, row0, w, l, nullptr, nullptr, out2, as_, ad_, es, ed);
}

// ---- fused scatter + gemm0: scatter blocks FIRST (blockIdx < SCAT_BLKS,
// partition = blockIdx&7, XCD-aligned), gemm0 blocks after. Index-ordered
// dispatch means scatter fills the machine first; its csr_src L2 lines fill
// and retire before the gemm stream floods L2 (overlap only in the tail). ----
__global__ __launch_bounds__(512) void scatter_gemm0_k(const int* __restrict__ src,
                                                       const int* __restrict__ dst,
                                                       int* __restrict__ cursor,
                                                       int* __restrict__ csr_src,
                                                       const float* __restrict__ x,
                                                       const float* __restrict__ W0,
                                                       ushort* __restrict__ out,
                                                       const float* __restrict__ as_,
                                                       const float* __restrict__ ad_,
                                                       float* __restrict__ es,
                                                       float* __restrict__ ed) {
  __shared__ uint As[128 * 64];   // 32 KB (gemm role only)
  __shared__ uint Wt[128 * 64];   // 32 KB
  if (blockIdx.x < SCAT_BLKS) {
    // ---- scatter role ----
    const int g = blockIdx.x & 7;          // physical-XCD-aligned partition
    const int chunk = blockIdx.x >> 3;     // 0..195
    const int lo = g * (NN / 8);
    const int hi = lo + (NN / 8);
    const int e0 = chunk * SG_CHUNK;
    const int e1 = (e0 + SG_CHUNK < NE) ? e0 + SG_CHUNK : NE;
    for (int i = e0 + threadIdx.x; i < e1; i += 512) {
      const int d = dst[i];
      if (d >= lo && d < hi) {
        const int pos = atomicAdd(&cursor[d], 1);
        csr_src[pos] = src[i];
      }
    }
  } else {
    // ---- gemm0 role ----
    const int gid = blockIdx.x - SCAT_BLKS;
    if (gid >= NG_GEMM) return;
    const int tid = threadIdx.x;
    const int row0 = gid * 128;
    stage_A_f32_nt(x, row0, As, tid);
    stage_W(W0, Wt, tid);
    __syncthreads();
    const int w = tid >> 6, l = tid & 63;
    bf16x8 afrag[4];
    load_afrag(As, w, l, afrag);
    mfma_write(Wt, afrag, row0, w, l, nullptr, nullptr, out, as_, ad_, es, ed);
  }
}

// ---- CSR build: XCD-partitioned histogram ----
__global__ __launch_bounds__(256) void hist_k(const int* __restrict__ dst, int* __restrict__ counts) {
  const int g = blockIdx.x & 7;
  const int chunk = blockIdx.x >> 3;
  const int lo = g * (NN / 8);
  const int hi = lo + (NN / 8);
  const int e0 = chunk * SC_CHUNK;
  const int e1 = (e0 + SC_CHUNK < NE) ? e0 + SC_CHUNK : NE;
  for (int i = e0 + threadIdx.x; i < e1; i += 256) {
    const int d = dst[i];
    if (d >= lo && d < hi) atomicAdd(&counts[d], 1);
  }
}

// ---- two-level scan ----
__global__ __launch_bounds__(256) void scan_blk_k(const int* __restrict__ counts,
                                                  int* __restrict__ row_start,
                                                  int* __restrict__ blocksum) {
  __shared__ int sm[256];
  const int t = threadIdx.x;
  const int i = blockIdx.x * 256 + t;
  const int c = (i < NN) ? counts[i] : 0;
  sm[t] = c;
  __syncthreads();
#pragma unroll
  for (int off = 1; off < 256; off <<= 1) {
    const int v = (t >= off) ? sm[t - off] : 0;
    __syncthreads();
    sm[t] += v;
    __syncthreads();
  }
  if (i < NN) row_start[i] = sm[t] - c;
  if (t == 255) blocksum[blockIdx.x] = sm[255];
}

__global__ __launch_bounds__(512) void scan_top_k(const int* __restrict__ blocksum,
                                                  int* __restrict__ blockoff) {
  __shared__ int sm[512];
  const int t = threadIdx.x;
  const int c = (t < NBLK) ? blocksum[t] : 0;
  sm[t] = c;
  __syncthreads();
#pragma unroll
  for (int off = 1; off < 512; off <<= 1) {
    const int v = (t >= off) ? sm[t - off] : 0;
    __syncthreads();
    sm[t] += v;
    __syncthreads();
  }
  if (t < NBLK) blockoff[t] = sm[t] - c;
}

__global__ __launch_bounds__(256) void scan_fix_k(int* __restrict__ row_start,
                                                  const int* __restrict__ blockoff,
                                                  int* __restrict__ cursor) {
  const int i = blockIdx.x * 256 + threadIdx.x;
  if (i < NN) {
    const int v = row_start[i] + blockoff[blockIdx.x];
    row_start[i] = v;
    cursor[i] = v;
  }
  if (i == 0) row_start[NN] = NE;
}

// ---- fused GAT aggregation: one wave per dst node, bf16 gathers, 8-way ILP ----
#define EDGE_BODY(sv)                                                      \
  {                                                                        \
    const int s_ = (sv);                                                   \
    float v_ = es[s_ * 4 + h] + edh;                                       \
    v_ = v_ > 0.f ? v_ : 0.2f * v_;                                        \
    const float w_ = __expf(v_);                                           \
    const uint m_ = xbf[(size_t)s_ * 64 + l];                              \
    den += w_;                                                             \
    ax = fmaf(w_, blo(m_), ax);                                            \
    ay = fmaf(w_, bhi(m_), ay);                                            \
  }

__global__ __launch_bounds__(256) void gat_agg_k(const int* __restrict__ row_start,
                                                 const int* __restrict__ csr_src,
                                                 const float* __restrict__ es,
                                                 const float* __restrict__ ed,
                                                 const uint* __restrict__ xbf,
                                                 const ushort* __restrict__ base,
                                                 const float* __restrict__ bias,
                                                 ushort* __restrict__ out) {
  const int wid = (blockIdx.x * 256 + threadIdx.x) >> 6;  // node id
  if (wid >= NN) return;
  const int l = threadIdx.x & 63;   // lane: channels 2l (lo), 2l+1 (hi)
  const int h = l >> 4;             // head of both channels
  const float edh = ed[wid * 4 + h];
  const int beg = row_start[wid], end = row_start[wid + 1];
  float ax = 0.f, ay = 0.f, den = 0.f;
  int i = beg;
  for (; i + 8 <= end; i += 8) {
    const int s0 = csr_src[i],     s1 = csr_src[i + 1];
    const int s2 = csr_src[i + 2], s3 = csr_src[i + 3];
    const int s4 = csr_src[i + 4], s5 = csr_src[i + 5];
    const int s6 = csr_src[i + 6], s7 = csr_src[i + 7];
    EDGE_BODY(s0) EDGE_BODY(s1) EDGE_BODY(s2) EDGE_BODY(s3)
    EDGE_BODY(s4) EDGE_BODY(s5) EDGE_BODY(s6) EDGE_BODY(s7)
  }
  for (; i + 4 <= end; i += 4) {
    const int s0 = csr_src[i],     s1 = csr_src[i + 1];
    const int s2 = csr_src[i + 2], s3 = csr_src[i + 3];
    EDGE_BODY(s0) EDGE_BODY(s1) EDGE_BODY(s2) EDGE_BODY(s3)
  }
  for (; i < end; i++) EDGE_BODY(csr_src[i]);

  const float inv = den > 0.f ? 1.f / den : 0.f;
  float rx = ax * inv, ry = ay * inv;
  const size_t o = (size_t)wid * 64 + l;   // uint index into bf16 row
  if (base) {
    const uint b = ((const uint*)base)[o];
    rx += blo(b); ry += bhi(b);
  }
  if (bias) { rx += bias[l * 2]; ry += bias[l * 2 + 1]; }
  ((uint*)out)[o] = pack2(rx, ry);
}

// ---- final projection via MFMA: out[N,32] = concat(h0,h1,h2) @ opW + opb ----
__global__ __launch_bounds__(512) void out_proj_k(const uint* __restrict__ h0,
                                                  const uint* __restrict__ h1,
                                                  const uint* __restrict__ h2,
                                                  const float* __restrict__ opW,
                                                  const float* __restrict__ opb,
                                                  float* __restrict__ out) {
  __shared__ uint As[128 * 64];   // 32 KB
  __shared__ uint Wt[32 * 192];   // 24 KB: Wt[n][k] bf16, n=0..31, k=0..383
  const int tid = threadIdx.x;
  const int row0 = blockIdx.x * 128;

  // stage opW[384][32] f32 -> Wt[n][384] bf16, XOR swizzle (n&7)<<2
#pragma unroll
  for (int i = 0; i < 3; i++) {
    const int cid = tid + 512 * i;        // 0..1535 = (n, k8)
    const int n = cid & 31;
    const int k8 = cid >> 5;              // 0..47
    float v[8];
#pragma unroll
    for (int j = 0; j < 8; j++) v[j] = opW[(size_t)(k8 * 8 + j) * 32 + n];
    uint4 p;
    p.x = pack2(v[0], v[1]);
    p.y = pack2(v[2], v[3]);
    p.z = pack2(v[4], v[5]);
    p.w = pack2(v[6], v[7]);
    const uint off = (uint)(n * 192 + k8 * 4) ^ (uint)((n & 7) << 2);
    *(uint4*)&Wt[off] = p;
  }

  const int w = tid >> 6, l = tid & 63;
  const int lrow = l & 15, lku = (l >> 4) * 4;
  f32x4 acc0 = {0.f, 0.f, 0.f, 0.f};
  f32x4 acc1 = {0.f, 0.f, 0.f, 0.f};
  const uint* __restrict__ hs[3] = {h0, h1, h2};

  for (int seg = 0; seg < 3; seg++) {
    __syncthreads();                       // prior As reads (and Wt stage) done
    stage_A_bf16(hs[seg], row0, As, tid);
    __syncthreads();
    bf16x8 afrag[4];
    load_afrag(As, w, l, afrag);
#pragma unroll
    for (int kc = 0; kc < 4; kc++) {
      const int n0 = lrow, n1 = 16 + lrow;
      const uint off0 = (uint)(n0 * 192 + seg * 64 + lku + kc * 16) ^ (uint)((n0 & 7) << 2);
      const uint off1 = (uint)(n1 * 192 + seg * 64 + lku + kc * 16) ^ (uint)((n1 & 7) << 2);
      const bf16x8 b0 = *(const bf16x8*)&Wt[off0];
      const bf16x8 b1 = *(const bf16x8*)&Wt[off1];
      acc0 = __builtin_amdgcn_mfma_f32_16x16x32_bf16(afrag[kc], b0, acc0, 0, 0, 0);
      acc1 = __builtin_amdgcn_mfma_f32_16x16x32_bf16(afrag[kc], b1, acc1, 0, 0, 0);
    }
  }

  const int r0 = row0 + w * 16 + (l >> 4) * 4;
  const float ba = opb[lrow], bb = opb[16 + lrow];
#pragma unroll
  for (int reg = 0; reg < 4; reg++) {
    const int r = r0 + reg;
    if (r < NN) {
      out[(size_t)r * 32 + lrow]      = acc0[reg] + ba;
      out[(size_t)r * 32 + 16 + lrow] = acc1[reg] + bb;
    }
  }
}

extern "C" void kernel_launch(void* const* d_in, const int* in_sizes, int n_in,
                              void* d_out, int out_size, void* d_ws, size_t ws_size,
                              hipStream_t stream) {
  (void)in_sizes; (void)n_in; (void)out_size; (void)ws_size;
  const float* x  = (const float*)d_in[0];
  const int*   ei = (const int*)d_in[1];
  const int*  src = ei;
  const int*  dst = ei + NE;
  const float *W0 = (const float*)d_in[2],  *as0 = (const float*)d_in[3],
              *ad0 = (const float*)d_in[4], *b0 = (const float*)d_in[5];
  const float *W1 = (const float*)d_in[6],  *as1 = (const float*)d_in[7],
              *ad1 = (const float*)d_in[8], *b1 = (const float*)d_in[9];
  const float *W2 = (const float*)d_in[10], *as2 = (const float*)d_in[11],
              *ad2 = (const float*)d_in[12], *b2 = (const float*)d_in[13];
  const float *llW = (const float*)d_in[14], *llb = (const float*)d_in[15];
  const float *opW = (const float*)d_in[16], *opb = (const float*)d_in[17];

  char* w = (char*)d_ws;
  ushort* h0b = (ushort*)w; w += (size_t)NHC * 2;
  ushort* h1b = (ushort*)w; w += (size_t)NHC * 2;
  ushort* h2b = (ushort*)w; w += (size_t)NHC * 2;
  uint*   xbf = (uint*)w;   w += (size_t)NHC * 2;   // NHC/2 uints (bf16 xh)
  float*  es  = (float*)w;  w += (size_t)NH4 * 4;
  float*  ed  = (float*)w;  w += (size_t)NH4 * 4;
  int* row_start = (int*)w; w += (size_t)(NN + 1) * 4;
  int* cursor    = (int*)w; w += (size_t)NN * 4;
  int* counts    = (int*)w; w += (size_t)NN * 4;
  int* csr_src   = (int*)w; w += (size_t)NE * 4;
  int* blocksum  = (int*)w; w += (size_t)NBLK * 4;
  int* blockoff  = (int*)w;

  const dim3 blk(256);
  // ---------- CSR build prefix (edges shared by all 3 layers) ----------
  hipMemsetAsync(counts, 0, (size_t)NN * 4, stream);
  hist_k<<<SC_NCHUNK * 8, blk, 0, stream>>>(dst, counts);
  scan_blk_k<<<NBLK, blk, 0, stream>>>(counts, row_start, blocksum);
  scan_top_k<<<1, 512, 0, stream>>>(blocksum, blockoff);
  scan_fix_k<<<NBLK, blk, 0, stream>>>(row_start, blockoff, cursor);
  // ---------- fused: scatter (first in grid) || layer-0 GEMM (after) ----------
  scatter_gemm0_k<<<SCAT_BLKS + NG_GEMM, 512, 0, stream>>>(src, dst, cursor, csr_src,
                                                           x, W0, (ushort*)xbf,
                                                           as0, ad0, es, ed);
  gat_agg_k<<<25000, blk, 0, stream>>>(row_start, csr_src, es, ed, xbf, nullptr, b0, h0b);
  // ---------- layer 1 ----------
  gemm128_k<true><<<782, 512, 0, stream>>>(h0b, W1, (ushort*)xbf, nullptr, nullptr,
                                           as1, ad1, es, ed);
  gat_agg_k<<<25000, blk, 0, stream>>>(row_start, csr_src, es, ed, xbf, h0b, b1, h1b);
  // ---------- layer 2: fused dual GEMM (shared A staging, fused attn) ----------
  gemm2_k<<<782, 512, 0, stream>>>((const uint*)h1b, llW, llb, b2, h2b, W2, (ushort*)xbf,
                                   as2, ad2, es, ed);
  gat_agg_k<<<25000, blk, 0, stream>>>(row_start, csr_src, es, ed, xbf, h2b, nullptr, h2b);
  // ---------- output head (MFMA) ----------
  out_proj_k<<<782, 512, 0, stream>>>((const uint*)h0b, (const uint*)h1b, (const uint*)h2b,
                                      opW, opb, (float*)d_out);
}

// Round 20
// 482.989 us; speedup vs baseline: 1.0339x; 1.0339x over previous
//
#include <hip/hip_runtime.h>
#include <hip/hip_bf16.h>

#define NN  100000
#define NE  1600000
#define NH4 400000      // N*H
#define NHC 12800000    // N*HC
#define NBLK 391        // ceil(NN/256)
#define SC_CHUNK 2048
#define SC_NCHUNK ((NE + SC_CHUNK - 1) / SC_CHUNK)  // 782 (hist)
#define SG_CHUNK 4096
#define SG_NCHUNK ((NE + SG_CHUNK - 1) / SG_CHUNK)  // 391 (fused scatter)
#define NG_GEMM 782

typedef __attribute__((ext_vector_type(8))) short bf16x8;
typedef __attribute__((ext_vector_type(4))) float f32x4;

__device__ __forceinline__ ushort f2bf(float f) {  // RNE f32 -> bf16 bits
  uint u = __float_as_uint(f);
  u += 0x7fff + ((u >> 16) & 1);
  return (ushort)(u >> 16);
}
__device__ __forceinline__ uint pack2(float a, float b) {
  return (uint)f2bf(a) | ((uint)f2bf(b) << 16);
}
__device__ __forceinline__ float blo(uint u) { return __uint_as_float(u << 16); }
__device__ __forceinline__ float bhi(uint u) { return __uint_as_float(u & 0xffff0000u); }

// ================= MFMA GEMM building blocks (128 rows/block, 8 waves) ======
__device__ __forceinline__ void stage_A_bf16(const uint* __restrict__ Ab, int row0,
                                             uint* __restrict__ As, int tid) {
  const uint4* __restrict__ Ag = (const uint4*)(Ab + (size_t)row0 * 64);
#pragma unroll
  for (int i = 0; i < 4; i++) {
    const int idx = tid + 512 * i;        // uint4 idx over 128x16
    const int r = idx >> 4, c4 = idx & 15;
    uint4 v = make_uint4(0u, 0u, 0u, 0u);
    if (row0 + r < NN) v = Ag[idx];
    const uint off = (uint)(r * 64 + c4 * 4) ^ (uint)((r & 7) << 2);
    *(uint4*)&As[off] = v;
  }
}
__device__ __forceinline__ void stage_A_f32(const float* __restrict__ Af, int row0,
                                            uint* __restrict__ As, int tid) {
  const float4* __restrict__ Ag = (const float4*)(Af + (size_t)row0 * 128);
#pragma unroll
  for (int i = 0; i < 8; i++) {
    const int idx = tid + 512 * i;        // float4 idx over 128x32
    const int r = idx >> 5, k4 = idx & 31;
    float4 a = make_float4(0.f, 0.f, 0.f, 0.f);
    if (row0 + r < NN) a = Ag[idx];
    uint2 p;
    p.x = pack2(a.x, a.y);
    p.y = pack2(a.z, a.w);
    const uint off = (uint)(r * 64 + k4 * 2) ^ (uint)((r & 7) << 2);
    *(uint2*)&As[off] = p;
  }
}
__device__ __forceinline__ void stage_W(const float* __restrict__ W,
                                        uint* __restrict__ Wt, int tid) {
#pragma unroll
  for (int i = 0; i < 4; i++) {
    const int cid = tid + 512 * i;        // (n, k8) chunk
    const int n = cid & 127;
    const int k8 = cid >> 7;              // 0..15
    float v[8];
#pragma unroll
    for (int j = 0; j < 8; j++) v[j] = W[(size_t)(k8 * 8 + j) * 128 + n];
    uint4 p;
    p.x = pack2(v[0], v[1]);
    p.y = pack2(v[2], v[3]);
    p.z = pack2(v[4], v[5]);
    p.w = pack2(v[6], v[7]);
    const uint off = (uint)(n * 64 + k8 * 4) ^ (uint)((n & 7) << 2);
    *(uint4*)&Wt[off] = p;
  }
}
__device__ __forceinline__ void load_afrag(const uint* __restrict__ As, int w, int l,
                                           bf16x8* afrag) {
  const int lrow = l & 15, lku = (l >> 4) * 4;
#pragma unroll
  for (int kc = 0; kc < 4; kc++) {
    const int r = w * 16 + lrow;
    const uint off = (uint)(r * 64 + lku + kc * 16) ^ (uint)((r & 7) << 2);
    afrag[kc] = *(const bf16x8*)&As[off];
  }
}

// MFMA + writeback; optionally fuses the attention-coefficient epilogue.
__device__ __forceinline__ void mfma_write(const uint* __restrict__ Wt,
                                           const bf16x8* afrag, int row0, int w, int l,
                                           const float* __restrict__ bias1,
                                           const float* __restrict__ bias2,
                                           ushort* __restrict__ out,
                                           const float* __restrict__ as_,
                                           const float* __restrict__ ad_,
                                           float* __restrict__ es,
                                           float* __restrict__ ed) {
  const int lrow = l & 15, lku = (l >> 4) * 4;
  const int r0 = row0 + w * 16 + (l >> 4) * 4;
#pragma unroll
  for (int pair = 0; pair < 4; pair++) {     // head index
    float pa[4] = {0.f, 0.f, 0.f, 0.f};
    float qa[4] = {0.f, 0.f, 0.f, 0.f};
#pragma unroll
    for (int sub = 0; sub < 2; sub++) {
      const int nt = pair * 2 + sub;
      const int n = nt * 16 + lrow;
      f32x4 acc = {0.f, 0.f, 0.f, 0.f};
#pragma unroll
      for (int kc = 0; kc < 4; kc++) {
        const uint off = (uint)(n * 64 + lku + kc * 16) ^ (uint)((n & 7) << 2);
        const bf16x8 bfrag = *(const bf16x8*)&Wt[off];
        acc = __builtin_amdgcn_mfma_f32_16x16x32_bf16(afrag[kc], bfrag, acc, 0, 0, 0);
      }
      float badd = 0.f;
      if (bias1) badd += bias1[n];
      if (bias2) badd += bias2[n];
#pragma unroll
      for (int reg = 0; reg < 4; reg++) {
        const int r = r0 + reg;
        if (r < NN) out[(size_t)r * 128 + n] = f2bf(acc[reg] + badd);
      }
      if (as_) {
        const float av = as_[n], dv = ad_[n];
#pragma unroll
        for (int reg = 0; reg < 4; reg++) {
          pa[reg] = fmaf(acc[reg], av, pa[reg]);
          qa[reg] = fmaf(acc[reg], dv, qa[reg]);
        }
      }
    }
    if (as_) {
#pragma unroll
      for (int m = 1; m <= 8; m <<= 1) {
#pragma unroll
        for (int reg = 0; reg < 4; reg++) {
          pa[reg] += __shfl_xor(pa[reg], m);
          qa[reg] += __shfl_xor(qa[reg], m);
        }
      }
      if (lrow == 0) {
#pragma unroll
        for (int reg = 0; reg < 4; reg++) {
          const int r = r0 + reg;
          if (r < NN) {
            es[r * 4 + pair] = pa[reg];
            ed[r * 4 + pair] = qa[reg];
          }
        }
      }
    }
  }
}

// ---- single GEMM: out = A @ W (+biases); optional fused attn coefs ----
template <bool ABF16>
__global__ __launch_bounds__(512) void gemm128_k(const void* __restrict__ Av,
                                                 const float* __restrict__ W,
                                                 ushort* __restrict__ out,
                                                 const float* __restrict__ bias1,
                                                 const float* __restrict__ bias2,
                                                 const float* __restrict__ as_,
                                                 const float* __restrict__ ad_,
                                                 float* __restrict__ es,
                                                 float* __restrict__ ed) {
  __shared__ uint As[128 * 64];   // 32 KB
  __shared__ uint Wt[128 * 64];   // 32 KB
  const int tid = threadIdx.x;
  const int row0 = blockIdx.x * 128;
  if constexpr (ABF16) stage_A_bf16((const uint*)Av, row0, As, tid);
  else                 stage_A_f32((const float*)Av, row0, As, tid);
  stage_W(W, Wt, tid);
  __syncthreads();
  const int w = tid >> 6, l = tid & 63;
  bf16x8 afrag[4];
  load_afrag(As, w, l, afrag);
  mfma_write(Wt, afrag, row0, w, l, bias1, bias2, out, as_, ad_, es, ed);
}

// ---- dual GEMM (layer 2): A staged once; Wt restaged in place ----
__global__ __launch_bounds__(512) void gemm2_k(const uint* __restrict__ Ab,
                                               const float* __restrict__ W1,
                                               const float* __restrict__ b1a,
                                               const float* __restrict__ b1b,
                                               ushort* __restrict__ out1,
                                               const float* __restrict__ W2,
                                               ushort* __restrict__ out2,
                                               const float* __restrict__ as_,
                                               const float* __restrict__ ad_,
                                               float* __restrict__ es,
                                               float* __restrict__ ed) {
  __shared__ uint As[128 * 64];   // 32 KB
  __shared__ uint Wt[128 * 64];   // 32 KB
  const int tid = threadIdx.x;
  const int row0 = blockIdx.x * 128;
  stage_A_bf16(Ab, row0, As, tid);
  stage_W(W1, Wt, tid);
  __syncthreads();
  const int w = tid >> 6, l = tid & 63;
  bf16x8 afrag[4];
  load_afrag(As, w, l, afrag);
  mfma_write(Wt, afrag, row0, w, l, b1a, b1b, out1, nullptr, nullptr, nullptr, nullptr);
  __syncthreads();                 // all Wt reads done
  stage_W(W2, Wt, tid);
  __syncthreads();
  mfma_write(Wt, afrag, row0, w, l, nullptr, nullptr, out2, as_, ad_, es, ed);
}

// ---- fused scatter + gemm0: one launch, concurrent role-split blocks.
// Period-40 interleave: blockIdx%40 < 8 -> gemm0 tile; else scatter chunk.
// Scatter partition stays blockIdx%8 (40%8==0 -> physical-XCD aligned,
// preserving the round-7 L2-local write property). ----
__global__ __launch_bounds__(512) void scatter_gemm0_k(const int* __restrict__ src,
                                                       const int* __restrict__ dst,
                                                       int* __restrict__ cursor,
                                                       int* __restrict__ csr_src,
                                                       const float* __restrict__ x,
                                                       const float* __restrict__ W0,
                                                       ushort* __restrict__ out,
                                                       const float* __restrict__ as_,
                                                       const float* __restrict__ ad_,
                                                       float* __restrict__ es,
                                                       float* __restrict__ ed) {
  __shared__ uint As[128 * 64];   // 32 KB (gemm role only)
  __shared__ uint Wt[128 * 64];   // 32 KB
  const int p = blockIdx.x / 40;
  const int within = blockIdx.x % 40;
  if (within < 8) {
    // ---- gemm0 role ----
    const int gid = p * 8 + within;
    if (gid >= NG_GEMM) return;
    const int tid = threadIdx.x;
    const int row0 = gid * 128;
    stage_A_f32(x, row0, As, tid);
    stage_W(W0, Wt, tid);
    __syncthreads();
    const int w = tid >> 6, l = tid & 63;
    bf16x8 afrag[4];
    load_afrag(As, w, l, afrag);
    mfma_write(Wt, afrag, row0, w, l, nullptr, nullptr, out, as_, ad_, es, ed);
  } else {
    // ---- scatter role ----
    const int g = blockIdx.x & 7;          // physical-XCD-aligned partition
    const int chunk = p * 4 + (within - 8) / 8;
    if (chunk >= SG_NCHUNK) return;
    const int lo = g * (NN / 8);
    const int hi = lo + (NN / 8);
    const int e0 = chunk * SG_CHUNK;
    const int e1 = (e0 + SG_CHUNK < NE) ? e0 + SG_CHUNK : NE;
    for (int i = e0 + threadIdx.x; i < e1; i += 512) {
      const int d = dst[i];
      if (d >= lo && d < hi) {
        const int pos = atomicAdd(&cursor[d], 1);
        csr_src[pos] = src[i];
      }
    }
  }
}

// ---- CSR build: XCD-partitioned histogram ----
__global__ __launch_bounds__(256) void hist_k(const int* __restrict__ dst, int* __restrict__ counts) {
  const int g = blockIdx.x & 7;
  const int chunk = blockIdx.x >> 3;
  const int lo = g * (NN / 8);
  const int hi = lo + (NN / 8);
  const int e0 = chunk * SC_CHUNK;
  const int e1 = (e0 + SC_CHUNK < NE) ? e0 + SC_CHUNK : NE;
  for (int i = e0 + threadIdx.x; i < e1; i += 256) {
    const int d = dst[i];
    if (d >= lo && d < hi) atomicAdd(&counts[d], 1);
  }
}

// ---- two-level scan ----
__global__ __launch_bounds__(256) void scan_blk_k(const int* __restrict__ counts,
                                                  int* __restrict__ row_start,
                                                  int* __restrict__ blocksum) {
  __shared__ int sm[256];
  const int t = threadIdx.x;
  const int i = blockIdx.x * 256 + t;
  const int c = (i < NN) ? counts[i] : 0;
  sm[t] = c;
  __syncthreads();
#pragma unroll
  for (int off = 1; off < 256; off <<= 1) {
    const int v = (t >= off) ? sm[t - off] : 0;
    __syncthreads();
    sm[t] += v;
    __syncthreads();
  }
  if (i < NN) row_start[i] = sm[t] - c;
  if (t == 255) blocksum[blockIdx.x] = sm[255];
}

__global__ __launch_bounds__(512) void scan_top_k(const int* __restrict__ blocksum,
                                                  int* __restrict__ blockoff) {
  __shared__ int sm[512];
  const int t = threadIdx.x;
  const int c = (t < NBLK) ? blocksum[t] : 0;
  sm[t] = c;
  __syncthreads();
#pragma unroll
  for (int off = 1; off < 512; off <<= 1) {
    const int v = (t >= off) ? sm[t - off] : 0;
    __syncthreads();
    sm[t] += v;
    __syncthreads();
  }
  if (t < NBLK) blockoff[t] = sm[t] - c;
}

__global__ __launch_bounds__(256) void scan_fix_k(int* __restrict__ row_start,
                                                  const int* __restrict__ blockoff,
                                                  int* __restrict__ cursor) {
  const int i = blockIdx.x * 256 + threadIdx.x;
  if (i < NN) {
    const int v = row_start[i] + blockoff[blockIdx.x];
    row_start[i] = v;
    cursor[i] = v;
  }
  if (i == 0) row_start[NN] = NE;
}

// ---- fused GAT aggregation: one wave per dst node, bf16 gathers, 8-way ILP ----
#define EDGE_BODY(sv)                                                      \
  {                                                                        \
    const int s_ = (sv);                                                   \
    float v_ = es[s_ * 4 + h] + edh;                                       \
    v_ = v_ > 0.f ? v_ : 0.2f * v_;                                        \
    const float w_ = __expf(v_);                                           \
    const uint m_ = xbf[(size_t)s_ * 64 + l];                              \
    den += w_;                                                             \
    ax = fmaf(w_, blo(m_), ax);                                            \
    ay = fmaf(w_, bhi(m_), ay);                                            \
  }

__global__ __launch_bounds__(256) void gat_agg_k(const int* __restrict__ row_start,
                                                 const int* __restrict__ csr_src,
                                                 const float* __restrict__ es,
                                                 const float* __restrict__ ed,
                                                 const uint* __restrict__ xbf,
                                                 const ushort* __restrict__ base,
                                                 const float* __restrict__ bias,
                                                 ushort* __restrict__ out) {
  const int wid = (blockIdx.x * 256 + threadIdx.x) >> 6;  // node id
  if (wid >= NN) return;
  const int l = threadIdx.x & 63;   // lane: channels 2l (lo), 2l+1 (hi)
  const int h = l >> 4;             // head of both channels
  const float edh = ed[wid * 4 + h];
  const int beg = row_start[wid], end = row_start[wid + 1];
  float ax = 0.f, ay = 0.f, den = 0.f;
  int i = beg;
  for (; i + 8 <= end; i += 8) {
    const int s0 = csr_src[i],     s1 = csr_src[i + 1];
    const int s2 = csr_src[i + 2], s3 = csr_src[i + 3];
    const int s4 = csr_src[i + 4], s5 = csr_src[i + 5];
    const int s6 = csr_src[i + 6], s7 = csr_src[i + 7];
    EDGE_BODY(s0) EDGE_BODY(s1) EDGE_BODY(s2) EDGE_BODY(s3)
    EDGE_BODY(s4) EDGE_BODY(s5) EDGE_BODY(s6) EDGE_BODY(s7)
  }
  for (; i + 4 <= end; i += 4) {
    const int s0 = csr_src[i],     s1 = csr_src[i + 1];
    const int s2 = csr_src[i + 2], s3 = csr_src[i + 3];
    EDGE_BODY(s0) EDGE_BODY(s1) EDGE_BODY(s2) EDGE_BODY(s3)
  }
  for (; i < end; i++) EDGE_BODY(csr_src[i]);

  const float inv = den > 0.f ? 1.f / den : 0.f;
  float rx = ax * inv, ry = ay * inv;
  const size_t o = (size_t)wid * 64 + l;   // uint index into bf16 row
  if (base) {
    const uint b = ((const uint*)base)[o];
    rx += blo(b); ry += bhi(b);
  }
  if (bias) { rx += bias[l * 2]; ry += bias[l * 2 + 1]; }
  ((uint*)out)[o] = pack2(rx, ry);
}

// ---- final projection via MFMA: out[N,32] = concat(h0,h1,h2) @ opW + opb ----
__global__ __launch_bounds__(512) void out_proj_k(const uint* __restrict__ h0,
                                                  const uint* __restrict__ h1,
                                                  const uint* __restrict__ h2,
                                                  const float* __restrict__ opW,
                                                  const float* __restrict__ opb,
                                                  float* __restrict__ out) {
  __shared__ uint As[128 * 64];   // 32 KB
  __shared__ uint Wt[32 * 192];   // 24 KB: Wt[n][k] bf16, n=0..31, k=0..383
  const int tid = threadIdx.x;
  const int row0 = blockIdx.x * 128;

  // stage opW[384][32] f32 -> Wt[n][384] bf16, XOR swizzle (n&7)<<2
#pragma unroll
  for (int i = 0; i < 3; i++) {
    const int cid = tid + 512 * i;        // 0..1535 = (n, k8)
    const int n = cid & 31;
    const int k8 = cid >> 5;              // 0..47
    float v[8];
#pragma unroll
    for (int j = 0; j < 8; j++) v[j] = opW[(size_t)(k8 * 8 + j) * 32 + n];
    uint4 p;
    p.x = pack2(v[0], v[1]);
    p.y = pack2(v[2], v[3]);
    p.z = pack2(v[4], v[5]);
    p.w = pack2(v[6], v[7]);
    const uint off = (uint)(n * 192 + k8 * 4) ^ (uint)((n & 7) << 2);
    *(uint4*)&Wt[off] = p;
  }

  const int w = tid >> 6, l = tid & 63;
  const int lrow = l & 15, lku = (l >> 4) * 4;
  f32x4 acc0 = {0.f, 0.f, 0.f, 0.f};
  f32x4 acc1 = {0.f, 0.f, 0.f, 0.f};
  const uint* __restrict__ hs[3] = {h0, h1, h2};

  for (int seg = 0; seg < 3; seg++) {
    __syncthreads();                       // prior As reads (and Wt stage) done
    stage_A_bf16(hs[seg], row0, As, tid);
    __syncthreads();
    bf16x8 afrag[4];
    load_afrag(As, w, l, afrag);
#pragma unroll
    for (int kc = 0; kc < 4; kc++) {
      const int n0 = lrow, n1 = 16 + lrow;
      const uint off0 = (uint)(n0 * 192 + seg * 64 + lku + kc * 16) ^ (uint)((n0 & 7) << 2);
      const uint off1 = (uint)(n1 * 192 + seg * 64 + lku + kc * 16) ^ (uint)((n1 & 7) << 2);
      const bf16x8 b0 = *(const bf16x8*)&Wt[off0];
      const bf16x8 b1 = *(const bf16x8*)&Wt[off1];
      acc0 = __builtin_amdgcn_mfma_f32_16x16x32_bf16(afrag[kc], b0, acc0, 0, 0, 0);
      acc1 = __builtin_amdgcn_mfma_f32_16x16x32_bf16(afrag[kc], b1, acc1, 0, 0, 0);
    }
  }

  const int r0 = row0 + w * 16 + (l >> 4) * 4;
  const float ba = opb[lrow], bb = opb[16 + lrow];
#pragma unroll
  for (int reg = 0; reg < 4; reg++) {
    const int r = r0 + reg;
    if (r < NN) {
      out[(size_t)r * 32 + lrow]      = acc0[reg] + ba;
      out[(size_t)r * 32 + 16 + lrow] = acc1[reg] + bb;
    }
  }
}

extern "C" void kernel_launch(void* const* d_in, const int* in_sizes, int n_in,
                              void* d_out, int out_size, void* d_ws, size_t ws_size,
                              hipStream_t stream) {
  (void)in_sizes; (void)n_in; (void)out_size; (void)ws_size;
  const float* x  = (const float*)d_in[0];
  const int*   ei = (const int*)d_in[1];
  const int*  src = ei;
  const int*  dst = ei + NE;
  const float *W0 = (const float*)d_in[2],  *as0 = (const float*)d_in[3],
              *ad0 = (const float*)d_in[4], *b0 = (const float*)d_in[5];
  const float *W1 = (const float*)d_in[6],  *as1 = (const float*)d_in[7],
              *ad1 = (const float*)d_in[8], *b1 = (const float*)d_in[9];
  const float *W2 = (const float*)d_in[10], *as2 = (const float*)d_in[11],
              *ad2 = (const float*)d_in[12], *b2 = (const float*)d_in[13];
  const float *llW = (const float*)d_in[14], *llb = (const float*)d_in[15];
  const float *opW = (const float*)d_in[16], *opb = (const float*)d_in[17];

  char* w = (char*)d_ws;
  ushort* h0b = (ushort*)w; w += (size_t)NHC * 2;
  ushort* h1b = (ushort*)w; w += (size_t)NHC * 2;
  ushort* h2b = (ushort*)w; w += (size_t)NHC * 2;
  uint*   xbf = (uint*)w;   w += (size_t)NHC * 2;   // NHC/2 uints (bf16 xh)
  float*  es  = (float*)w;  w += (size_t)NH4 * 4;
  float*  ed  = (float*)w;  w += (size_t)NH4 * 4;
  int* row_start = (int*)w; w += (size_t)(NN + 1) * 4;
  int* cursor    = (int*)w; w += (size_t)NN * 4;
  int* counts    = (int*)w; w += (size_t)NN * 4;
  int* csr_src   = (int*)w; w += (size_t)NE * 4;
  int* blocksum  = (int*)w; w += (size_t)NBLK * 4;
  int* blockoff  = (int*)w;

  const dim3 blk(256);
  // ---------- CSR build prefix (edges shared by all 3 layers) ----------
  hipMemsetAsync(counts, 0, (size_t)NN * 4, stream);
  hist_k<<<SC_NCHUNK * 8, blk, 0, stream>>>(dst, counts);
  scan_blk_k<<<NBLK, blk, 0, stream>>>(counts, row_start, blocksum);
  scan_top_k<<<1, 512, 0, stream>>>(blocksum, blockoff);
  scan_fix_k<<<NBLK, blk, 0, stream>>>(row_start, blockoff, cursor);
  // ---------- fused: scatter (CSR finalize) || layer-0 GEMM ----------
  scatter_gemm0_k<<<98 * 40, 512, 0, stream>>>(src, dst, cursor, csr_src,
                                               x, W0, (ushort*)xbf, as0, ad0, es, ed);
  gat_agg_k<<<25000, blk, 0, stream>>>(row_start, csr_src, es, ed, xbf, nullptr, b0, h0b);
  // ---------- layer 1 ----------
  gemm128_k<true><<<782, 512, 0, stream>>>(h0b, W1, (ushort*)xbf, nullptr, nullptr,
                                           as1, ad1, es, ed);
  gat_agg_k<<<25000, blk, 0, stream>>>(row_start, csr_src, es, ed, xbf, h0b, b1, h1b);
  // ---------- layer 2: fused dual GEMM (shared A staging, fused attn) ----------
  gemm2_k<<<782, 512, 0, stream>>>((const uint*)h1b, llW, llb, b2, h2b, W2, (ushort*)xbf,
                                   as2, ad2, es, ed);
  gat_agg_k<<<25000, blk, 0, stream>>>(row_start, csr_src, es, ed, xbf, h2b, nullptr, h2b);
  // ---------- output head (MFMA) ----------
  out_proj_k<<<782, 512, 0, stream>>>((const uint*)h0b, (const uint*)h1b, (const uint*)h2b,
                                      opW, opb, (float*)d_out);
}